// Round 5
// baseline (185.282 us; speedup 1.0000x reference)
//
#include <hip/hip_runtime.h>
#include <hip/hip_bf16.h>
#include <math.h>

typedef unsigned long long u64;
typedef unsigned int u32;
typedef __hip_bfloat16 bf16;

#define N 1024
#define NCLS 21
#define APP 1024
#define DF 128
#define NH 16
#define DK 64
#define NS 4     // n-splits in flash attention

typedef __attribute__((ext_vector_type(8))) short short8v;
typedef __attribute__((ext_vector_type(4))) float float4v;
union U4S8 { uint4 u; short8v s; };

__device__ __forceinline__ float b2f(bf16 x) { return __bfloat162float(x); }
__device__ __forceinline__ ushort f2bu(float x) { bf16 b = __float2bfloat16(x); return *(ushort*)&b; }
__device__ __forceinline__ float bu2f(ushort u) { return __uint_as_float(((uint)u) << 16); }

// ---------------------------------------------------------------- k_prep
__global__ void k_prep(const float* __restrict__ roi, const float* __restrict__ cls_loc,
                       const float* __restrict__ score, const int* __restrict__ size,
                       const float* __restrict__ wgw,
                       float* __restrict__ prob, int* __restrict__ label,
                       float* __restrict__ bbox, u64* __restrict__ keys,
                       ushort* __restrict__ wgwb)
{
    int i = blockIdx.x * 256 + threadIdx.x;
    if (i >= N) return;
    // one-time bf16 conversion of wgw [16][64] (exactly 1024 elements)
    wgwb[i] = f2bu(wgw[i]);

    float s[NCLS];
    float mx = -1e30f; int am = 0;
    for (int c = 0; c < NCLS; c++) {
        s[c] = score[i * NCLS + c];
        if (s[c] > mx) { mx = s[c]; am = c; }
    }
    float sum = 0.f;
    for (int c = 0; c < NCLS; c++) sum += expf(s[c] - mx);
    float p = 1.0f / sum;

    float y0 = roi[i*4+0], x0 = roi[i*4+1];
    float y1 = roi[i*4+2], x1 = roi[i*4+3];
    float hh = y1 - y0, ww = x1 - x0;
    float cy = y0 + 0.5f * hh, cx = x0 + 0.5f * ww;
    float l0 = cls_loc[i*84 + am*4 + 0] * 0.1f;
    float l1 = cls_loc[i*84 + am*4 + 1] * 0.1f;
    float l2 = cls_loc[i*84 + am*4 + 2] * 0.2f;
    float l3 = cls_loc[i*84 + am*4 + 3] * 0.2f;
    float ncy = l0 * hh + cy, ncx = l1 * ww + cx;
    float nh = expf(l2) * hh, nw = expf(l3) * ww;
    float b0 = ncy - 0.5f * nh, b1 = ncx - 0.5f * nw;
    float b2v = ncy + 0.5f * nh, b3 = ncx + 0.5f * nw;
    float lim = ((am & 1) == 0) ? (float)size[0] : (float)size[1];
    b0  = fminf(fmaxf(b0, 0.f), lim);
    b1  = fminf(fmaxf(b1, 0.f), lim);
    b2v = fminf(fmaxf(b2v, 0.f), lim);
    b3  = fminf(fmaxf(b3, 0.f), lim);
    prob[i] = p; label[i] = am;
    bbox[i*4+0] = b0; bbox[i*4+1] = b1; bbox[i*4+2] = b2v; bbox[i*4+3] = b3;
    keys[i] = ((u64)(0xFFFFFFFFu - __float_as_uint(p)) << 32) | (u32)i;
}

// ---------------------------------------------------------------- k_rank
__global__ void __launch_bounds__(256) k_rank(
        const u64* __restrict__ keys, const float* __restrict__ prob,
        const int* __restrict__ label, const float* __restrict__ bbox,
        int* __restrict__ order, float* __restrict__ sprob,
        float* __restrict__ sbbox, float* __restrict__ sgeo,
        float* __restrict__ out)
{
    __shared__ u64 sk[N];
    int t = threadIdx.x;
    int i = blockIdx.x * 256 + t;
    for (int j = t; j < N; j += 256) sk[j] = keys[j];
    __syncthreads();
    u64 my = sk[i];
    int r = 0;
    for (int j = 0; j < N; j++) r += (sk[j] < my) ? 1 : 0;
    order[r] = i;
    sprob[r] = prob[i];
    float b0 = bbox[i*4+0], b1 = bbox[i*4+1], b2 = bbox[i*4+2], b3 = bbox[i*4+3];
    sbbox[r*4+0] = b0; sbbox[r*4+1] = b1; sbbox[r*4+2] = b2; sbbox[r*4+3] = b3;
    // per-box geo precompute: (cx, cy, log w, log h) in sorted order
    sgeo[r*4+0] = (b0 + b2) * 0.5f;
    sgeo[r*4+1] = (b1 + b3) * 0.5f;
    sgeo[r*4+2] = __logf(b2 - b0 + 1.0f);
    sgeo[r*4+3] = __logf(b3 - b1 + 1.0f);
    out[N + r] = (float)(label[i] - 1);
    out[2*N + r*4 + 0] = b0;
    out[2*N + r*4 + 1] = b1;
    out[2*N + r*4 + 2] = b2;
    out[2*N + r*4 + 3] = b3;
}

// ---------------------------------------------------------------- k_geoemb (horizontal fusion)
// blocks 0..255: emb body FIRST (16 rt x 8 dg x 2 ph) -> part  (overlaps geo)
// blocks 256..1279: geo body, ONE block per m, 16-iter inner loop -> lw
__global__ void __launch_bounds__(256) k_geoemb(
        const int* __restrict__ order, const float* __restrict__ app,
        const float* __restrict__ feat_w, const float* __restrict__ rank_w,
        float* __restrict__ part,
        const float* __restrict__ sbbox, const float* __restrict__ sgeo,
        const ushort* __restrict__ wgwb,
        const float* __restrict__ wgb, bf16* __restrict__ lw)
{
    __shared__ __align__(16) char smem[27904];
    int bx = blockIdx.x, t = threadIdx.x;
    int w = t >> 6, l = t & 63, l15 = l & 15, quad = l >> 4;

    if (bx >= 256) {
        // ===================== geo body =====================
        uint (*sOut)[260] = (uint(*)[260])smem;   // 16 x 260 x 4 = 16640 B
        int m = bx - 256;

        // block-uniform m-side scalars
        float4 mg = *(const float4*)&sgeo[m*4];   // cx, cy, logw, logh
        float4 mb = *(const float4*)&sbbox[m*4];
        float wm = mb.z - mb.x + 1.0f, hm = mb.w - mb.y + 1.0f;

        // per-lane quad-dependent constants (hoisted out of the loop)
        float sC  = (quad == 0) ? mg.x : (quad == 1) ? mg.y : 0.0f;
        float sM  = ((quad & 1) == 0) ? 1e-3f * wm : 1e-3f * hm;
        float sL  = ((quad & 1) == 0) ? mg.z : mg.w;   // log wm / log hm
        float sSg = (quad < 2) ? 100.0f : -100.0f;

        // pre-converted bf16 geo weights: 2 vector loads
        U4S8 Bg0, Bg1;
        const uint4* wg4 = (const uint4*)wgwb;
        Bg0.u = wg4[l15*8 + quad];
        Bg1.u = wg4[l15*8 + 4 + quad];
        float bias = wgb[l15];

        const float dmt[8] = { 1.0f, 0.42169650342f, 0.177827941f, 0.0749894209f,
                               0.0316227766f, 0.01333521432f, 0.00562341325f, 0.00237137371f };

        uint* lwu = (uint*)lw;
        for (int half = 0; half < 2; half++) {
            #pragma unroll 4
            for (int mt2i = 0; mt2i < 8; mt2i++) {
                int mt2 = half*8 + mt2i;
                int n = mt2*64 + w*16 + l15;
                float valn = sgeo[n*4 + quad];            // 4B load, pipelined
                float lg = __logf(fmaxf(fabsf(sC - valn), sM));
                float lv = (quad < 2) ? lg : valn;        // q2/3: precomputed log wn / log hn
                float P  = sSg * (lv - sL);               // = 100*pos component

                U4S8 Af0, Af1;   // sin half (g=0..31), cos half (g=32..63)
                #pragma unroll
                for (int j = 0; j < 4; j++) {
                    float s0, c0, s1, c1;
                    __sincosf(P * dmt[2*j],     &s0, &c0);
                    __sincosf(P * dmt[2*j + 1], &s1, &c1);
                    ((uint*)&Af0)[j] = (uint)f2bu(s0) | ((uint)f2bu(s1) << 16);
                    ((uint*)&Af1)[j] = (uint)f2bu(c0) | ((uint)f2bu(c1) << 16);
                }

                float4v c = (float4v){0.f, 0.f, 0.f, 0.f};
                c = __builtin_amdgcn_mfma_f32_16x16x32_bf16(Af0.s, Bg0.s, c, 0, 0, 0);
                c = __builtin_amdgcn_mfma_f32_16x16x32_bf16(Af1.s, Bg1.s, c, 0, 0, 0);
                float v0 = __logf(fmaxf(c[0] + bias, 1e-6f));
                float v1 = __logf(fmaxf(c[1] + bias, 1e-6f));
                float v2 = __logf(fmaxf(c[2] + bias, 1e-6f));
                float v3 = __logf(fmaxf(c[3] + bias, 1e-6f));
                int pb = mt2i*32 + w*8 + quad*2;
                sOut[l15][pb]     = (uint)f2bu(v0) | ((uint)f2bu(v1) << 16);
                sOut[l15][pb + 1] = (uint)f2bu(v2) | ((uint)f2bu(v3) << 16);
            }
            __syncthreads();
            // write out this half: 16 h x 256 uints = 1024 uint4
            #pragma unroll
            for (int it = 0; it < 4; it++) {
                int idx = t + it * 256;            // 0..1023
                int hh = idx >> 6, col4 = idx & 63;
                uint4 val = *(const uint4*)&sOut[hh][col4*4];
                *(uint4*)&lwu[((size_t)hh << 19) + ((size_t)m << 9) + half*256 + col4*4] = val;
            }
            __syncthreads();
        }
    } else {
        // ===================== emb body =====================
        ushort (*sA)[72] = (ushort(*)[72])smem;             // 9216 B
        ushort (*sW)[72] = (ushort(*)[72])(smem + 9216);    // 18432 B
        int* sOrd = (int*)(smem + 27648);                   // 256 B
        int idx0 = bx;
        int rt = idx0 & 15, dg = (idx0 >> 4) & 7, ph = idx0 >> 7;
        int r0 = rt * 64;
        if (t < 64) sOrd[t] = order[r0 + t];
        __syncthreads();

        const float* Wsrc = ph ? rank_w : feat_w;
        float4v acc[8];
        #pragma unroll
        for (int nb = 0; nb < 8; nb++) acc[nb] = (float4v){0.f, 0.f, 0.f, 0.f};

        for (int dc = dg * 2; dc < dg * 2 + 2; dc++) {
            int d0 = dc * 64;
            #pragma unroll
            for (int it = 0; it < 32; it++) {
                int idx = t + it * 256;
                int d = idx >> 7, c = idx & 127;
                sW[c][d] = f2bu(Wsrc[(size_t)(d0 + d) * 128 + c]);
            }
            if (ph == 0) {
                #pragma unroll
                for (int it = 0; it < 16; it++) {
                    int idx = t + it * 256;
                    int r = idx >> 6, d = idx & 63;
                    sA[r][d] = f2bu(app[(size_t)sOrd[r] * 1024 + d0 + d]);
                }
            } else {
                #pragma unroll
                for (int it = 0; it < 16; it++) {
                    int idx = t + it * 256;
                    int r = idx >> 6, d = idx & 63;
                    int dgl = d0 + d;
                    float irow = (float)(r0 + r);
                    float val;
                    if (dgl < 512) val = __sinf(irow * exp2f(-(float)dgl * 0.019464422f));
                    else           val = __cosf(irow * exp2f(-(float)(dgl - 512) * 0.019464422f));
                    sA[r][d] = f2bu(val);
                }
            }
            __syncthreads();
            U4S8 Af0, Af1;
            Af0.u = *(uint4*)&sA[w*16 + l15][quad*8];
            Af1.u = *(uint4*)&sA[w*16 + l15][32 + quad*8];
            #pragma unroll
            for (int nb = 0; nb < 8; nb++) {
                U4S8 Bf0, Bf1;
                Bf0.u = *(uint4*)&sW[nb*16 + l15][quad*8];
                Bf1.u = *(uint4*)&sW[nb*16 + l15][32 + quad*8];
                acc[nb] = __builtin_amdgcn_mfma_f32_16x16x32_bf16(Af0.s, Bf0.s, acc[nb], 0, 0, 0);
                acc[nb] = __builtin_amdgcn_mfma_f32_16x16x32_bf16(Af1.s, Bf1.s, acc[nb], 0, 0, 0);
            }
            __syncthreads();
        }
        #pragma unroll
        for (int reg = 0; reg < 4; reg++) {
            int row = r0 + w*16 + quad*4 + reg;
            #pragma unroll
            for (int nb = 0; nb < 8; nb++)
                part[(((size_t)ph * 8 + dg) * 1024 + row) * 128 + nb*16 + l15] = acc[nb][reg];
        }
    }
}

// ---------------------------------------------------------------- k_embsum (-> bf16)  + weight pre-convert
// blocks 0..511: embb = sum(part) + biases
// blocks 512..2047: wqkvt[mat][h][kk][d] = bf16(W[mat][h][d][kk])  (transposed, 768 KB)
__global__ void k_embsum(const float* __restrict__ part,
                         const float* __restrict__ feat_b, const float* __restrict__ rank_b,
                         bf16* __restrict__ embb,
                         const float* __restrict__ wq, const float* __restrict__ wk,
                         const float* __restrict__ wv, ushort* __restrict__ wqkvt)
{
    int b = blockIdx.x, t = threadIdx.x;
    if (b < 512) {
        int gid = b * 256 + t;
        int c = gid & 127;
        float acc = feat_b[c] + rank_b[c];
        #pragma unroll
        for (int p8 = 0; p8 < 16; p8++) acc += part[(size_t)p8 * 131072 + gid];
        embb[gid] = __float2bfloat16(acc);
    } else {
        int lin = (b - 512) * 256 + t;        // 0..393215 ; d fastest -> writes coalesced
        int mat = lin >> 17;
        int rem = lin & 131071;
        int h   = rem >> 13;
        int rem2 = rem & 8191;
        int kk  = rem2 >> 7;
        int d   = rem2 & 127;
        const float* W = (mat == 0) ? wq : (mat == 1) ? wk : wv;
        wqkvt[lin] = f2bu(W[(((size_t)h * 128 + d) << 6) + kk]);
    }
}

// ---------------------------------------------------------------- k_qkv2 (MFMA, no LDS)
__global__ void __launch_bounds__(256) k_qkv2(
        const bf16* __restrict__ embb, const ushort* __restrict__ wqkvt,
        const float* __restrict__ bq, const float* __restrict__ bk,
        const float* __restrict__ bv,
        bf16* __restrict__ q, bf16* __restrict__ k, bf16* __restrict__ v)
{
    int t = threadIdx.x;
    int rt = blockIdx.x, h = blockIdx.y, mat = blockIdx.z;
    const float* Bb = (mat == 0) ? bq : (mat == 1) ? bk : bv;
    bf16* Out       = (mat == 0) ? q  : (mat == 1) ? k  : v;
    int w = t >> 6, l = t & 63, l15 = l & 15, quad = l >> 4;

    // B-fragments straight from pre-transposed bf16 weights [kk][d] (row = 16 uint4)
    const uint4* Wt4 = (const uint4*)(wqkvt + ((size_t)(mat * 16 + h) << 13));
    U4S8 Bf[4][4];
    #pragma unroll
    for (int nb = 0; nb < 4; nb++)
        #pragma unroll
        for (int kc = 0; kc < 4; kc++)
            Bf[nb][kc].u = Wt4[(nb*16 + l15) * 16 + kc*4 + quad];

    float biasv[4];
    #pragma unroll
    for (int nb = 0; nb < 4; nb++) biasv[nb] = Bb[h * 64 + nb*16 + l15];

    const uint4* A4 = (const uint4*)embb;
    int r0 = rt * 128 + w * 32;
    ushort* outu = (ushort*)Out;
    for (int mb = 0; mb < 2; mb++) {
        int arow = r0 + mb*16 + l15;
        U4S8 Af[4];
        #pragma unroll
        for (int kc = 0; kc < 4; kc++) Af[kc].u = A4[(size_t)arow * 16 + kc*4 + quad];
        float4v acc[4];
        #pragma unroll
        for (int nb = 0; nb < 4; nb++) acc[nb] = (float4v){0.f, 0.f, 0.f, 0.f};
        #pragma unroll
        for (int kc = 0; kc < 4; kc++)
            #pragma unroll
            for (int nb = 0; nb < 4; nb++)
                acc[nb] = __builtin_amdgcn_mfma_f32_16x16x32_bf16(Af[kc].s, Bf[nb][kc].s, acc[nb], 0, 0, 0);
        #pragma unroll
        for (int reg = 0; reg < 4; reg++) {
            int orow = r0 + mb*16 + quad*4 + reg;
            #pragma unroll
            for (int nb = 0; nb < 4; nb++)
                outu[((size_t)h * N + orow) * 64 + nb*16 + l15] = f2bu(acc[nb][reg] + biasv[nb]);
        }
    }
}

// ---------------------------------------------------------------- k_attn4 (MFMA flash, n-split)
// Q fragments loaded direct from global (row-major layout == fragment layout);
// only V-transpose and lw stay LDS-staged. LDS 27.6 KB -> 5 blocks/CU.
__global__ void __launch_bounds__(256) k_attn4(
        const bf16* __restrict__ q, const bf16* __restrict__ kmat,
        const bf16* __restrict__ v, const bf16* __restrict__ lw,
        bf16* __restrict__ opartb, float* __restrict__ mpart, float* __restrict__ zpart)
{
    __shared__ uint sVtu[64][36];
    __shared__ uint slwu[64][36];
    __shared__ uint sPu[4][16][36];

    int t = threadIdx.x;
    int mt = blockIdx.x, h = blockIdx.y, ns = blockIdx.z;
    int m0 = mt * 64;
    int w = t >> 6, l = t & 63, l15 = l & 15, quad = l >> 4;

    U4S8 kf0, kf1;
    const uint4* k4 = (const uint4*)kmat;
    const uint4* q4 = (const uint4*)q;
    {
        size_t krow = ((size_t)h * N + m0 + w*16 + l15) * 8;
        kf0.u = k4[krow + quad];
        kf1.u = k4[krow + 4 + quad];
    }

    float4v O[4];
    float M[4], Z[4];
    #pragma unroll
    for (int i = 0; i < 4; i++) {
        O[i] = (float4v){0.f, 0.f, 0.f, 0.f};
        M[i] = -1e30f; Z[i] = 0.f;
    }

    const uint* vsrc = (const uint*)v;
    const uint* lwsrc = (const uint*)lw;

    for (int tile = ns * (16/NS); tile < (ns + 1) * (16/NS); tile++) {
        int n0 = tile * 64;
        #pragma unroll
        for (int i = 0; i < 4; i++) {
            int idx = t + i * 256;
            int a = idx & 31, nh2 = idx >> 5;
            uint g0 = vsrc[((size_t)h * N + n0 + 2*nh2) * 32 + a];
            uint g1 = vsrc[((size_t)h * N + n0 + 2*nh2 + 1) * 32 + a];
            sVtu[2*a][nh2]     = (g0 & 0xFFFFu) | (g1 << 16);
            sVtu[2*a + 1][nh2] = (g0 >> 16) | (g1 & 0xFFFF0000u);
        }
        #pragma unroll
        for (int i = 0; i < 8; i++) {
            int idx = t + i * 256;
            int mi = idx >> 5, np = idx & 31;
            slwu[mi][np] = lwsrc[((size_t)h << 19) + ((size_t)(m0 + mi) << 9) + (n0 >> 1) + np];
        }
        __syncthreads();

        float4v S[4];
        #pragma unroll
        for (int nb = 0; nb < 4; nb++) {
            U4S8 bq0, bq1;
            size_t qrow = ((size_t)h * N + n0 + nb*16 + l15) * 8;
            bq0.u = q4[qrow + quad];
            bq1.u = q4[qrow + 4 + quad];
            float4v zz = (float4v){0.f, 0.f, 0.f, 0.f};
            float4v p0 = __builtin_amdgcn_mfma_f32_16x16x32_bf16(kf0.s, bq0.s, zz, 0, 0, 0);
            S[nb] = __builtin_amdgcn_mfma_f32_16x16x32_bf16(kf1.s, bq1.s, p0, 0, 0, 0);
        }
        ushort* pRow[4];
        #pragma unroll
        for (int r = 0; r < 4; r++) pRow[r] = (ushort*)&sPu[w][quad*4 + r][0];
        #pragma unroll
        for (int r = 0; r < 4; r++) {
            int mi = w*16 + quad*4 + r;
            float sv[4];
            #pragma unroll
            for (int nb = 0; nb < 4; nb++) {
                int col = nb*16 + l15;
                uint lu = slwu[mi][col >> 1];
                float lv = (col & 1) ? __uint_as_float(lu & 0xFFFF0000u)
                                     : __uint_as_float(lu << 16);
                sv[nb] = S[nb][r] * 0.125f + lv;
            }
            float rm = fmaxf(fmaxf(sv[0], sv[1]), fmaxf(sv[2], sv[3]));
            #pragma unroll
            for (int off = 1; off < 16; off <<= 1)
                rm = fmaxf(rm, __shfl_xor(rm, off, 64));
            float newM = fmaxf(M[r], rm);
            float pr[4], rs = 0.f;
            #pragma unroll
            for (int nb = 0; nb < 4; nb++) {
                pr[nb] = __expf(sv[nb] - newM);
                rs += pr[nb];
            }
            #pragma unroll
            for (int off = 1; off < 16; off <<= 1)
                rs += __shfl_xor(rs, off, 64);
            float sc = __expf(M[r] - newM);
            M[r] = newM;
            Z[r] = Z[r] * sc + rs;
            #pragma unroll
            for (int kvb = 0; kvb < 4; kvb++) O[kvb][r] *= sc;
            #pragma unroll
            for (int nb = 0; nb < 4; nb++)
                pRow[r][nb*16 + l15] = f2bu(pr[nb]);
        }
        {
            U4S8 ap0, ap1;
            ap0.u = *(uint4*)&sPu[w][l15][quad*4];
            ap1.u = *(uint4*)&sPu[w][l15][16 + quad*4];
            #pragma unroll
            for (int kvb = 0; kvb < 4; kvb++) {
                U4S8 bv0, bv1;
                bv0.u = *(uint4*)&sVtu[kvb*16 + l15][quad*4];
                bv1.u = *(uint4*)&sVtu[kvb*16 + l15][16 + quad*4];
                O[kvb] = __builtin_amdgcn_mfma_f32_16x16x32_bf16(ap0.s, bv0.s, O[kvb], 0, 0, 0);
                O[kvb] = __builtin_amdgcn_mfma_f32_16x16x32_bf16(ap1.s, bv1.s, O[kvb], 0, 0, 0);
            }
        }
        __syncthreads();
    }

    ushort* ob = (ushort*)opartb;
    #pragma unroll
    for (int r = 0; r < 4; r++) {
        int m = m0 + w*16 + quad*4 + r;
        size_t row = ((size_t)ns * NH + h) * N + m;
        #pragma unroll
        for (int kvb = 0; kvb < 4; kvb++)
            ob[row * 64 + kvb*16 + l15] = f2bu(O[kvb][r]);
        if (l15 == 0) { mpart[row] = M[r]; zpart[row] = Z[r]; }
    }
}

// ---------------------------------------------------------------- k_final2 (merge + logit)
__global__ void __launch_bounds__(128) k_final2(
        const bf16* __restrict__ opartb, const float* __restrict__ mpart,
        const float* __restrict__ zpart, const int* __restrict__ order,
        const float* __restrict__ app, const float* __restrict__ lw,
        const float* __restrict__ lb, const float* __restrict__ sprob,
        float* __restrict__ out)
{
    __shared__ float sWgt[NH][NS];
    __shared__ float sInvZ[NH];
    __shared__ float red[2];
    int m = blockIdx.x, t = threadIdx.x;
    if (t < NH) {
        int h = t;
        float Ms[NS], Mg = -1e30f;
        #pragma unroll
        for (int ns = 0; ns < NS; ns++) {
            Ms[ns] = mpart[(size_t)ns * 16384 + h * 1024 + m];
            Mg = fmaxf(Mg, Ms[ns]);
        }
        float Zt = 0.f;
        #pragma unroll
        for (int ns = 0; ns < NS; ns++) {
            float wgt = __expf(Ms[ns] - Mg);
            sWgt[h][ns] = wgt;
            Zt += zpart[(size_t)ns * 16384 + h * 1024 + m] * wgt;
        }
        sInvZ[h] = 1.0f / Zt;
    }
    __syncthreads();
    int o = order[m];
    const ushort* ob = (const ushort*)opartb;
    float s = 0.f;
    for (int j = t; j < APP; j += 128) {
        int hh = j >> 6, kk = j & 63;
        size_t base = ((size_t)hh * 1024 + m) * 64 + kk;
        float val = 0.f;
        #pragma unroll
        for (int ns = 0; ns < NS; ns++)
            val += bu2f(ob[(size_t)ns * 1048576 + base]) * sWgt[hh][ns];
        float rv = val * sInvZ[hh] + app[o * APP + j];
        s += rv * lw[j];
    }
    #pragma unroll
    for (int off = 32; off > 0; off >>= 1) s += __shfl_down(s, off, 64);
    if ((t & 63) == 0) red[t >> 6] = s;
    __syncthreads();
    if (t == 0) {
        float tot = red[0] + red[1] + lb[0];
        float s1 = 1.0f / (1.0f + expf(-tot));
        out[m] = s1 * sprob[m];
    }
}

// ---------------------------------------------------------------- launch
extern "C" void kernel_launch(void* const* d_in, const int* in_sizes, int n_in,
                              void* d_out, int out_size, void* d_ws, size_t ws_size,
                              hipStream_t stream)
{
    const float* roi      = (const float*)d_in[0];
    const float* cls_loc  = (const float*)d_in[1];
    const float* score    = (const float*)d_in[2];
    const float* app      = (const float*)d_in[3];
    const int*   size     = (const int*)d_in[4];
    const float* rank_w   = (const float*)d_in[5];
    const float* rank_b   = (const float*)d_in[6];
    const float* feat_w   = (const float*)d_in[7];
    const float* feat_b   = (const float*)d_in[8];
    const float* logit_w  = (const float*)d_in[9];
    const float* logit_b  = (const float*)d_in[10];
    const float* wg_w     = (const float*)d_in[11];
    const float* wg_b     = (const float*)d_in[12];
    const float* wk_w     = (const float*)d_in[13];
    const float* wk_b     = (const float*)d_in[14];
    const float* wq_w     = (const float*)d_in[15];
    const float* wq_b     = (const float*)d_in[16];
    const float* wv_w     = (const float*)d_in[17];
    const float* wv_b     = (const float*)d_in[18];
    float* out = (float*)d_out;

    char* ws = (char*)d_ws;
    float* prob  = (float*)(ws + 0);
    int*   label = (int*)  (ws + 4096);
    float* bbox  = (float*)(ws + 8192);
    u64*   keys  = (u64*)  (ws + 24576);
    int*   order = (int*)  (ws + 32768);
    float* sprob = (float*)(ws + 36864);
    float* sbbox = (float*)(ws + 40960);
    bf16*  embb  = (bf16*) (ws + 57344);      // 256 KB
    ushort* wgwb = (ushort*)(ws + 1048576);   // 2 KB   bf16 wgw [16][64]
    float* sgeo  = (float*)(ws + 1052672);    // 16 KB  (cx,cy,logw,logh) sorted
    ushort* wqkvt= (ushort*)(ws + 2097152);   // 768 KB bf16 [3][16][64][128] transposed
    bf16*  q     = (bf16*) (ws + 8970240);    // 2 MB
    bf16*  k     = (bf16*) (ws + 11067392);   // 2 MB
    bf16*  v     = (bf16*) (ws + 13164544);   // 2 MB
    bf16*  lwbuf = (bf16*) (ws + 17358848);   // 32 MB
    float* part  = (float*)(ws + 50913280);   // 8 MB   [16][1024][128] f32
    bf16*  opartb= (bf16*) (ws + 67690496);   // 8 MB   [NS][16384][64] bf16
    float* mpart = (float*)(ws + 84467712);   // 256 KB [NS][16384]
    float* zpart = (float*)(ws + 84729856);   // 256 KB

    k_prep<<<4, 256, 0, stream>>>(roi, cls_loc, score, size, wg_w, prob, label, bbox, keys, wgwb);
    k_rank<<<4, 256, 0, stream>>>(keys, prob, label, bbox, order, sprob, sbbox, sgeo, out);
    k_geoemb<<<1280, 256, 0, stream>>>(order, app, feat_w, rank_w, part,
                                       sbbox, sgeo, wgwb, wg_b, lwbuf);
    k_embsum<<<2048, 256, 0, stream>>>(part, feat_b, rank_b, embb, wq_w, wk_w, wv_w, wqkvt);
    k_qkv2<<<dim3(8, 16, 3), 256, 0, stream>>>(embb, wqkvt, wq_b, wk_b, wv_b, q, k, v);
    k_attn4<<<dim3(16, 16, NS), 256, 0, stream>>>(q, k, v, lwbuf, opartb, mpart, zpart);
    k_final2<<<1024, 128, 0, stream>>>(opartb, mpart, zpart, order, app, logit_w, logit_b, sprob, out);
}

// Round 6
// 168.338 us; speedup vs baseline: 1.1007x; 1.1007x over previous
//
#include <hip/hip_runtime.h>
#include <hip/hip_bf16.h>
#include <math.h>

typedef unsigned long long u64;
typedef unsigned int u32;
typedef __hip_bfloat16 bf16;

#define N 1024
#define NCLS 21
#define APP 1024
#define DF 128
#define NH 16
#define DK 64
#define NS 2     // n-splits in flash attention

typedef __attribute__((ext_vector_type(8))) short short8v;
typedef __attribute__((ext_vector_type(4))) float float4v;
union U4S8 { uint4 u; short8v s; };

__device__ __forceinline__ float b2f(bf16 x) { return __bfloat162float(x); }
__device__ __forceinline__ ushort f2bu(float x) { bf16 b = __float2bfloat16(x); return *(ushort*)&b; }
__device__ __forceinline__ float bu2f(ushort u) { return __uint_as_float(((uint)u) << 16); }

// ---------------------------------------------------------------- k_prep
__global__ void k_prep(const float* __restrict__ roi, const float* __restrict__ cls_loc,
                       const float* __restrict__ score, const int* __restrict__ size,
                       const float* __restrict__ wgw,
                       float* __restrict__ prob, int* __restrict__ label,
                       float* __restrict__ bbox, u64* __restrict__ keys,
                       ushort* __restrict__ wgwb)
{
    int i = blockIdx.x * 256 + threadIdx.x;
    if (i >= N) return;
    // one-time bf16 conversion of wgw [16][64] (exactly 1024 elements)
    wgwb[i] = f2bu(wgw[i]);

    float s[NCLS];
    float mx = -1e30f; int am = 0;
    for (int c = 0; c < NCLS; c++) {
        s[c] = score[i * NCLS + c];
        if (s[c] > mx) { mx = s[c]; am = c; }
    }
    float sum = 0.f;
    for (int c = 0; c < NCLS; c++) sum += expf(s[c] - mx);
    float p = 1.0f / sum;

    float y0 = roi[i*4+0], x0 = roi[i*4+1];
    float y1 = roi[i*4+2], x1 = roi[i*4+3];
    float hh = y1 - y0, ww = x1 - x0;
    float cy = y0 + 0.5f * hh, cx = x0 + 0.5f * ww;
    float l0 = cls_loc[i*84 + am*4 + 0] * 0.1f;
    float l1 = cls_loc[i*84 + am*4 + 1] * 0.1f;
    float l2 = cls_loc[i*84 + am*4 + 2] * 0.2f;
    float l3 = cls_loc[i*84 + am*4 + 3] * 0.2f;
    float ncy = l0 * hh + cy, ncx = l1 * ww + cx;
    float nh = expf(l2) * hh, nw = expf(l3) * ww;
    float b0 = ncy - 0.5f * nh, b1 = ncx - 0.5f * nw;
    float b2v = ncy + 0.5f * nh, b3 = ncx + 0.5f * nw;
    float lim = ((am & 1) == 0) ? (float)size[0] : (float)size[1];
    b0  = fminf(fmaxf(b0, 0.f), lim);
    b1  = fminf(fmaxf(b1, 0.f), lim);
    b2v = fminf(fmaxf(b2v, 0.f), lim);
    b3  = fminf(fmaxf(b3, 0.f), lim);
    prob[i] = p; label[i] = am;
    bbox[i*4+0] = b0; bbox[i*4+1] = b1; bbox[i*4+2] = b2v; bbox[i*4+3] = b3;
    keys[i] = ((u64)(0xFFFFFFFFu - __float_as_uint(p)) << 32) | (u32)i;
}

// ---------------------------------------------------------------- k_rank (4-way split count)
// 16 blocks x 256 threads; 4 threads per ranked element, each counting a
// 256-key quarter of the LDS key array, combined with two shfl_xor adds.
__global__ void __launch_bounds__(256) k_rank(
        const u64* __restrict__ keys, const float* __restrict__ prob,
        const int* __restrict__ label, const float* __restrict__ bbox,
        int* __restrict__ order, float* __restrict__ sprob,
        float* __restrict__ sbbox, float* __restrict__ sgeo,
        float* __restrict__ out)
{
    __shared__ u64 sk[N];
    int t = threadIdx.x;
    for (int j = t; j < N; j += 256) sk[j] = keys[j];
    __syncthreads();
    int il = t >> 2, q = t & 3;           // 64 elements/block, 4 counters each
    int i = blockIdx.x * 64 + il;
    u64 my = sk[i];
    int r = 0;
    int j0 = q * 256;
    #pragma unroll 8
    for (int j = j0; j < j0 + 256; j++) r += (sk[j] < my) ? 1 : 0;
    r += __shfl_xor(r, 1, 64);
    r += __shfl_xor(r, 2, 64);
    if (q == 0) {
        order[r] = i;
        sprob[r] = prob[i];
        float b0 = bbox[i*4+0], b1 = bbox[i*4+1], b2 = bbox[i*4+2], b3 = bbox[i*4+3];
        sbbox[r*4+0] = b0; sbbox[r*4+1] = b1; sbbox[r*4+2] = b2; sbbox[r*4+3] = b3;
        // per-box geo precompute: (cx, cy, log w, log h) in sorted order
        sgeo[r*4+0] = (b0 + b2) * 0.5f;
        sgeo[r*4+1] = (b1 + b3) * 0.5f;
        sgeo[r*4+2] = __logf(b2 - b0 + 1.0f);
        sgeo[r*4+3] = __logf(b3 - b1 + 1.0f);
        out[N + r] = (float)(label[i] - 1);
        out[2*N + r*4 + 0] = b0;
        out[2*N + r*4 + 1] = b1;
        out[2*N + r*4 + 2] = b2;
        out[2*N + r*4 + 3] = b3;
    }
}

// ---------------------------------------------------------------- k_geoemb (horizontal fusion)
// blocks 0..255: emb body FIRST (16 rt x 8 dg x 2 ph) -> part  (overlaps geo)
// blocks 256..1279: geo body, ONE block per m, 16-iter inner loop -> lw
__global__ void __launch_bounds__(256) k_geoemb(
        const int* __restrict__ order, const float* __restrict__ app,
        const float* __restrict__ feat_w, const float* __restrict__ rank_w,
        float* __restrict__ part,
        const float* __restrict__ sbbox, const float* __restrict__ sgeo,
        const ushort* __restrict__ wgwb,
        const float* __restrict__ wgb, bf16* __restrict__ lw)
{
    __shared__ __align__(16) char smem[33024];
    int bx = blockIdx.x, t = threadIdx.x;
    int w = t >> 6, l = t & 63, l15 = l & 15, quad = l >> 4;

    if (bx >= 256) {
        // ===================== geo body =====================
        uint (*sOut)[516] = (uint(*)[516])smem;   // 16 x 516 x 4 = 33024 B
        int m = bx - 256;

        // block-uniform m-side scalars
        float4 mg = *(const float4*)&sgeo[m*4];   // cx, cy, logw, logh
        float4 mb = *(const float4*)&sbbox[m*4];
        float wm = mb.z - mb.x + 1.0f, hm = mb.w - mb.y + 1.0f;

        // per-lane quad-dependent constants (hoisted out of the loop)
        float sC  = (quad == 0) ? mg.x : (quad == 1) ? mg.y : 0.0f;
        float sM  = ((quad & 1) == 0) ? 1e-3f * wm : 1e-3f * hm;
        float sL  = ((quad & 1) == 0) ? mg.z : mg.w;   // log wm / log hm
        float sSg = (quad < 2) ? 100.0f : -100.0f;

        // pre-converted bf16 geo weights: 2 vector loads
        U4S8 Bg0, Bg1;
        const uint4* wg4 = (const uint4*)wgwb;
        Bg0.u = wg4[l15*8 + quad];
        Bg1.u = wg4[l15*8 + 4 + quad];
        float bias = wgb[l15];

        const float dmt[8] = { 1.0f, 0.42169650342f, 0.177827941f, 0.0749894209f,
                               0.0316227766f, 0.01333521432f, 0.00562341325f, 0.00237137371f };

        #pragma unroll 4
        for (int mt2 = 0; mt2 < 16; mt2++) {
            int n = mt2*64 + w*16 + l15;
            float valn = sgeo[n*4 + quad];            // 4B load, pipelined by unroll
            float lg = __logf(fmaxf(fabsf(sC - valn), sM));
            float lv = (quad < 2) ? lg : valn;        // q2/3: precomputed log wn / log hn
            float P  = sSg * (lv - sL);               // = 100*pos component

            U4S8 Af0, Af1;   // sin half (g=0..31), cos half (g=32..63)
            #pragma unroll
            for (int j = 0; j < 4; j++) {
                float s0, c0, s1, c1;
                __sincosf(P * dmt[2*j],     &s0, &c0);
                __sincosf(P * dmt[2*j + 1], &s1, &c1);
                ((uint*)&Af0)[j] = (uint)f2bu(s0) | ((uint)f2bu(s1) << 16);
                ((uint*)&Af1)[j] = (uint)f2bu(c0) | ((uint)f2bu(c1) << 16);
            }

            float4v c = (float4v){0.f, 0.f, 0.f, 0.f};
            c = __builtin_amdgcn_mfma_f32_16x16x32_bf16(Af0.s, Bg0.s, c, 0, 0, 0);
            c = __builtin_amdgcn_mfma_f32_16x16x32_bf16(Af1.s, Bg1.s, c, 0, 0, 0);
            float v0 = __logf(fmaxf(c[0] + bias, 1e-6f));
            float v1 = __logf(fmaxf(c[1] + bias, 1e-6f));
            float v2 = __logf(fmaxf(c[2] + bias, 1e-6f));
            float v3 = __logf(fmaxf(c[3] + bias, 1e-6f));
            int pb = mt2*32 + w*8 + quad*2;
            sOut[l15][pb]     = (uint)f2bu(v0) | ((uint)f2bu(v1) << 16);
            sOut[l15][pb + 1] = (uint)f2bu(v2) | ((uint)f2bu(v3) << 16);
        }
        __syncthreads();
        uint* lwu = (uint*)lw;
        #pragma unroll
        for (int it = 0; it < 8; it++) {
            int idx = t + it * 256;            // 2048 uint4 = 16 h x 128
            int hh = idx >> 7, col4 = idx & 127;
            uint4 val = *(const uint4*)&sOut[hh][col4*4];
            *(uint4*)&lwu[((size_t)hh << 19) + ((size_t)m << 9) + col4*4] = val;
        }
    } else {
        // ===================== emb body =====================
        ushort (*sA)[72] = (ushort(*)[72])smem;             // 9216 B
        ushort (*sW)[72] = (ushort(*)[72])(smem + 9216);    // 18432 B
        int* sOrd = (int*)(smem + 27648);                   // 256 B
        int idx0 = bx;
        int rt = idx0 & 15, dg = (idx0 >> 4) & 7, ph = idx0 >> 7;
        int r0 = rt * 64;
        if (t < 64) sOrd[t] = order[r0 + t];
        __syncthreads();

        const float* Wsrc = ph ? rank_w : feat_w;
        float4v acc[8];
        #pragma unroll
        for (int nb = 0; nb < 8; nb++) acc[nb] = (float4v){0.f, 0.f, 0.f, 0.f};

        for (int dc = dg * 2; dc < dg * 2 + 2; dc++) {
            int d0 = dc * 64;
            #pragma unroll
            for (int it = 0; it < 32; it++) {
                int idx = t + it * 256;
                int d = idx >> 7, c = idx & 127;
                sW[c][d] = f2bu(Wsrc[(size_t)(d0 + d) * 128 + c]);
            }
            if (ph == 0) {
                #pragma unroll
                for (int it = 0; it < 16; it++) {
                    int idx = t + it * 256;
                    int r = idx >> 6, d = idx & 63;
                    sA[r][d] = f2bu(app[(size_t)sOrd[r] * 1024 + d0 + d]);
                }
            } else {
                #pragma unroll
                for (int it = 0; it < 16; it++) {
                    int idx = t + it * 256;
                    int r = idx >> 6, d = idx & 63;
                    int dgl = d0 + d;
                    float irow = (float)(r0 + r);
                    float val;
                    if (dgl < 512) val = __sinf(irow * exp2f(-(float)dgl * 0.019464422f));
                    else           val = __cosf(irow * exp2f(-(float)(dgl - 512) * 0.019464422f));
                    sA[r][d] = f2bu(val);
                }
            }
            __syncthreads();
            U4S8 Af0, Af1;
            Af0.u = *(uint4*)&sA[w*16 + l15][quad*8];
            Af1.u = *(uint4*)&sA[w*16 + l15][32 + quad*8];
            #pragma unroll
            for (int nb = 0; nb < 8; nb++) {
                U4S8 Bf0, Bf1;
                Bf0.u = *(uint4*)&sW[nb*16 + l15][quad*8];
                Bf1.u = *(uint4*)&sW[nb*16 + l15][32 + quad*8];
                acc[nb] = __builtin_amdgcn_mfma_f32_16x16x32_bf16(Af0.s, Bf0.s, acc[nb], 0, 0, 0);
                acc[nb] = __builtin_amdgcn_mfma_f32_16x16x32_bf16(Af1.s, Bf1.s, acc[nb], 0, 0, 0);
            }
            __syncthreads();
        }
        #pragma unroll
        for (int reg = 0; reg < 4; reg++) {
            int row = r0 + w*16 + quad*4 + reg;
            #pragma unroll
            for (int nb = 0; nb < 8; nb++)
                part[(((size_t)ph * 8 + dg) * 1024 + row) * 128 + nb*16 + l15] = acc[nb][reg];
        }
    }
}

// ---------------------------------------------------------------- k_embsum (-> bf16)
__global__ void k_embsum(const float* __restrict__ part,
                         const float* __restrict__ feat_b, const float* __restrict__ rank_b,
                         bf16* __restrict__ embb)
{
    int gid = blockIdx.x * 256 + threadIdx.x;
    int c = gid & 127;
    float acc = feat_b[c] + rank_b[c];
    #pragma unroll
    for (int p8 = 0; p8 < 16; p8++) acc += part[(size_t)p8 * 131072 + gid];
    embb[gid] = __float2bfloat16(acc);
}

// ---------------------------------------------------------------- k_qkv2 (MFMA)
__global__ void __launch_bounds__(256) k_qkv2(
        const bf16* __restrict__ embb,
        const float* __restrict__ wq, const float* __restrict__ bq,
        const float* __restrict__ wk, const float* __restrict__ bk,
        const float* __restrict__ wv, const float* __restrict__ bv,
        bf16* __restrict__ q, bf16* __restrict__ k, bf16* __restrict__ v)
{
    __shared__ ushort sWt[64][136];
    int t = threadIdx.x;
    int rt = blockIdx.x, h = blockIdx.y, mat = blockIdx.z;
    const float* W  = (mat == 0) ? wq : (mat == 1) ? wk : wv;
    const float* Bb = (mat == 0) ? bq : (mat == 1) ? bk : bv;
    bf16* Out       = (mat == 0) ? q  : (mat == 1) ? k  : v;

    #pragma unroll
    for (int i = 0; i < 32; i++) {
        int idx = t + i * 256;
        int d = idx >> 6, kk = idx & 63;
        sWt[kk][d] = f2bu(W[((size_t)h * 128 + d) * 64 + kk]);
    }
    int w = t >> 6, l = t & 63, l15 = l & 15, quad = l >> 4;
    float biasv[4];
    #pragma unroll
    for (int nb = 0; nb < 4; nb++) biasv[nb] = Bb[h * 64 + nb*16 + l15];
    __syncthreads();

    U4S8 Bf[4][4];
    #pragma unroll
    for (int nb = 0; nb < 4; nb++)
        #pragma unroll
        for (int kc = 0; kc < 4; kc++)
            Bf[nb][kc].u = *(uint4*)&sWt[nb*16 + l15][kc*32 + quad*8];

    const uint4* A4 = (const uint4*)embb;
    int r0 = rt * 128 + w * 32;
    ushort* outu = (ushort*)Out;
    for (int mb = 0; mb < 2; mb++) {
        int arow = r0 + mb*16 + l15;
        U4S8 Af[4];
        #pragma unroll
        for (int kc = 0; kc < 4; kc++) Af[kc].u = A4[(size_t)arow * 16 + kc*4 + quad];
        float4v acc[4];
        #pragma unroll
        for (int nb = 0; nb < 4; nb++) acc[nb] = (float4v){0.f, 0.f, 0.f, 0.f};
        #pragma unroll
        for (int kc = 0; kc < 4; kc++)
            #pragma unroll
            for (int nb = 0; nb < 4; nb++)
                acc[nb] = __builtin_amdgcn_mfma_f32_16x16x32_bf16(Af[kc].s, Bf[nb][kc].s, acc[nb], 0, 0, 0);
        #pragma unroll
        for (int reg = 0; reg < 4; reg++) {
            int orow = r0 + mb*16 + quad*4 + reg;
            #pragma unroll
            for (int nb = 0; nb < 4; nb++)
                outu[((size_t)h * N + orow) * 64 + nb*16 + l15] = f2bu(acc[nb][reg] + biasv[nb]);
        }
    }
}

// ---------------------------------------------------------------- k_attn4 (MFMA flash, n-split)
__global__ void __launch_bounds__(256) k_attn4(
        const bf16* __restrict__ q, const bf16* __restrict__ kmat,
        const bf16* __restrict__ v, const bf16* __restrict__ lw,
        bf16* __restrict__ opartb, float* __restrict__ mpart, float* __restrict__ zpart)
{
    __shared__ uint sQu[64][36];
    __shared__ uint sVtu[64][36];
    __shared__ uint slwu[64][36];
    __shared__ uint sPu[4][16][36];

    int t = threadIdx.x;
    int mt = blockIdx.x, h = blockIdx.y, ns = blockIdx.z;
    int m0 = mt * 64;
    int w = t >> 6, l = t & 63, l15 = l & 15, quad = l >> 4;

    U4S8 kf0, kf1;
    {
        const uint4* k4 = (const uint4*)kmat;
        size_t krow = ((size_t)h * N + m0 + w*16 + l15) * 8;
        kf0.u = k4[krow + quad];
        kf1.u = k4[krow + 4 + quad];
    }

    float4v O[4];
    float M[4], Z[4];
    #pragma unroll
    for (int i = 0; i < 4; i++) {
        O[i] = (float4v){0.f, 0.f, 0.f, 0.f};
        M[i] = -1e30f; Z[i] = 0.f;
    }

    const uint* qsrc = (const uint*)q;
    const uint* vsrc = (const uint*)v;
    const uint* lwsrc = (const uint*)lw;

    for (int tile = ns * (16/NS); tile < (ns + 1) * (16/NS); tile++) {
        int n0 = tile * 64;
        #pragma unroll
        for (int i = 0; i < 8; i++) {
            int idx = t + i * 256;
            int nj = idx >> 5, kp = idx & 31;
            sQu[nj][kp] = qsrc[((size_t)h * N + n0 + nj) * 32 + kp];
        }
        #pragma unroll
        for (int i = 0; i < 4; i++) {
            int idx = t + i * 256;
            int a = idx & 31, nh2 = idx >> 5;
            uint g0 = vsrc[((size_t)h * N + n0 + 2*nh2) * 32 + a];
            uint g1 = vsrc[((size_t)h * N + n0 + 2*nh2 + 1) * 32 + a];
            sVtu[2*a][nh2]     = (g0 & 0xFFFFu) | (g1 << 16);
            sVtu[2*a + 1][nh2] = (g0 >> 16) | (g1 & 0xFFFF0000u);
        }
        #pragma unroll
        for (int i = 0; i < 8; i++) {
            int idx = t + i * 256;
            int mi = idx >> 5, np = idx & 31;
            slwu[mi][np] = lwsrc[((size_t)h << 19) + ((size_t)(m0 + mi) << 9) + (n0 >> 1) + np];
        }
        __syncthreads();

        float4v S[4];
        #pragma unroll
        for (int nb = 0; nb < 4; nb++) {
            U4S8 bq0, bq1;
            bq0.u = *(uint4*)&sQu[nb*16 + l15][quad*4];
            bq1.u = *(uint4*)&sQu[nb*16 + l15][16 + quad*4];
            float4v zz = (float4v){0.f, 0.f, 0.f, 0.f};
            float4v p0 = __builtin_amdgcn_mfma_f32_16x16x32_bf16(kf0.s, bq0.s, zz, 0, 0, 0);
            S[nb] = __builtin_amdgcn_mfma_f32_16x16x32_bf16(kf1.s, bq1.s, p0, 0, 0, 0);
        }
        ushort* pRow[4];
        #pragma unroll
        for (int r = 0; r < 4; r++) pRow[r] = (ushort*)&sPu[w][quad*4 + r][0];
        #pragma unroll
        for (int r = 0; r < 4; r++) {
            int mi = w*16 + quad*4 + r;
            float sv[4];
            #pragma unroll
            for (int nb = 0; nb < 4; nb++) {
                int col = nb*16 + l15;
                uint lu = slwu[mi][col >> 1];
                float lv = (col & 1) ? __uint_as_float(lu & 0xFFFF0000u)
                                     : __uint_as_float(lu << 16);
                sv[nb] = S[nb][r] * 0.125f + lv;
            }
            float rm = fmaxf(fmaxf(sv[0], sv[1]), fmaxf(sv[2], sv[3]));
            #pragma unroll
            for (int off = 1; off < 16; off <<= 1)
                rm = fmaxf(rm, __shfl_xor(rm, off, 64));
            float newM = fmaxf(M[r], rm);
            float pr[4], rs = 0.f;
            #pragma unroll
            for (int nb = 0; nb < 4; nb++) {
                pr[nb] = __expf(sv[nb] - newM);
                rs += pr[nb];
            }
            #pragma unroll
            for (int off = 1; off < 16; off <<= 1)
                rs += __shfl_xor(rs, off, 64);
            float sc = __expf(M[r] - newM);
            M[r] = newM;
            Z[r] = Z[r] * sc + rs;
            #pragma unroll
            for (int kvb = 0; kvb < 4; kvb++) O[kvb][r] *= sc;
            #pragma unroll
            for (int nb = 0; nb < 4; nb++)
                pRow[r][nb*16 + l15] = f2bu(pr[nb]);
        }
        {
            U4S8 ap0, ap1;
            ap0.u = *(uint4*)&sPu[w][l15][quad*4];
            ap1.u = *(uint4*)&sPu[w][l15][16 + quad*4];
            #pragma unroll
            for (int kvb = 0; kvb < 4; kvb++) {
                U4S8 bv0, bv1;
                bv0.u = *(uint4*)&sVtu[kvb*16 + l15][quad*4];
                bv1.u = *(uint4*)&sVtu[kvb*16 + l15][16 + quad*4];
                O[kvb] = __builtin_amdgcn_mfma_f32_16x16x32_bf16(ap0.s, bv0.s, O[kvb], 0, 0, 0);
                O[kvb] = __builtin_amdgcn_mfma_f32_16x16x32_bf16(ap1.s, bv1.s, O[kvb], 0, 0, 0);
            }
        }
        __syncthreads();
    }

    ushort* ob = (ushort*)opartb;
    #pragma unroll
    for (int r = 0; r < 4; r++) {
        int m = m0 + w*16 + quad*4 + r;
        size_t row = ((size_t)ns * NH + h) * N + m;
        #pragma unroll
        for (int kvb = 0; kvb < 4; kvb++)
            ob[row * 64 + kvb*16 + l15] = f2bu(O[kvb][r]);
        if (l15 == 0) { mpart[row] = M[r]; zpart[row] = Z[r]; }
    }
}

// ---------------------------------------------------------------- k_final2 (merge + logit)
__global__ void __launch_bounds__(128) k_final2(
        const bf16* __restrict__ opartb, const float* __restrict__ mpart,
        const float* __restrict__ zpart, const int* __restrict__ order,
        const float* __restrict__ app, const float* __restrict__ lw,
        const float* __restrict__ lb, const float* __restrict__ sprob,
        float* __restrict__ out)
{
    __shared__ float sWgt[NH][NS];
    __shared__ float sInvZ[NH];
    __shared__ float red[2];
    int m = blockIdx.x, t = threadIdx.x;
    if (t < NH) {
        int h = t;
        float Ms[NS], Mg = -1e30f;
        #pragma unroll
        for (int ns = 0; ns < NS; ns++) {
            Ms[ns] = mpart[(size_t)ns * 16384 + h * 1024 + m];
            Mg = fmaxf(Mg, Ms[ns]);
        }
        float Zt = 0.f;
        #pragma unroll
        for (int ns = 0; ns < NS; ns++) {
            float wgt = __expf(Ms[ns] - Mg);
            sWgt[h][ns] = wgt;
            Zt += zpart[(size_t)ns * 16384 + h * 1024 + m] * wgt;
        }
        sInvZ[h] = 1.0f / Zt;
    }
    __syncthreads();
    int o = order[m];
    const ushort* ob = (const ushort*)opartb;
    float s = 0.f;
    for (int j = t; j < APP; j += 128) {
        int hh = j >> 6, kk = j & 63;
        size_t base = ((size_t)hh * 1024 + m) * 64 + kk;
        float val = 0.f;
        #pragma unroll
        for (int ns = 0; ns < NS; ns++)
            val += bu2f(ob[(size_t)ns * 1048576 + base]) * sWgt[hh][ns];
        float rv = val * sInvZ[hh] + app[o * APP + j];
        s += rv * lw[j];
    }
    #pragma unroll
    for (int off = 32; off > 0; off >>= 1) s += __shfl_down(s, off, 64);
    if ((t & 63) == 0) red[t >> 6] = s;
    __syncthreads();
    if (t == 0) {
        float tot = red[0] + red[1] + lb[0];
        float s1 = 1.0f / (1.0f + expf(-tot));
        out[m] = s1 * sprob[m];
    }
}

// ---------------------------------------------------------------- launch
extern "C" void kernel_launch(void* const* d_in, const int* in_sizes, int n_in,
                              void* d_out, int out_size, void* d_ws, size_t ws_size,
                              hipStream_t stream)
{
    const float* roi      = (const float*)d_in[0];
    const float* cls_loc  = (const float*)d_in[1];
    const float* score    = (const float*)d_in[2];
    const float* app      = (const float*)d_in[3];
    const int*   size     = (const int*)d_in[4];
    const float* rank_w   = (const float*)d_in[5];
    const float* rank_b   = (const float*)d_in[6];
    const float* feat_w   = (const float*)d_in[7];
    const float* feat_b   = (const float*)d_in[8];
    const float* logit_w  = (const float*)d_in[9];
    const float* logit_b  = (const float*)d_in[10];
    const float* wg_w     = (const float*)d_in[11];
    const float* wg_b     = (const float*)d_in[12];
    const float* wk_w     = (const float*)d_in[13];
    const float* wk_b     = (const float*)d_in[14];
    const float* wq_w     = (const float*)d_in[15];
    const float* wq_b     = (const float*)d_in[16];
    const float* wv_w     = (const float*)d_in[17];
    const float* wv_b     = (const float*)d_in[18];
    float* out = (float*)d_out;

    char* ws = (char*)d_ws;
    float* prob  = (float*)(ws + 0);
    int*   label = (int*)  (ws + 4096);
    float* bbox  = (float*)(ws + 8192);
    u64*   keys  = (u64*)  (ws + 24576);
    int*   order = (int*)  (ws + 32768);
    float* sprob = (float*)(ws + 36864);
    float* sbbox = (float*)(ws + 40960);
    bf16*  embb  = (bf16*) (ws + 57344);      // 256 KB
    ushort* wgwb = (ushort*)(ws + 1048576);   // 2 KB   bf16 wgw [16][64]
    float* sgeo  = (float*)(ws + 1052672);    // 16 KB  (cx,cy,logw,logh) sorted
    bf16*  q     = (bf16*) (ws + 8970240);    // 2 MB
    bf16*  k     = (bf16*) (ws + 11067392);   // 2 MB
    bf16*  v     = (bf16*) (ws + 13164544);   // 2 MB
    bf16*  lwbuf = (bf16*) (ws + 17358848);   // 32 MB
    float* part  = (float*)(ws + 50913280);   // 8 MB   [16][1024][128] f32
    bf16*  opartb= (bf16*) (ws + 67690496);   // 4 MB   [NS][16384][64] bf16
    float* mpart = (float*)(ws + 84467712);   // 128 KB [NS][16384]
    float* zpart = (float*)(ws + 84729856);   // 128 KB

    k_prep<<<4, 256, 0, stream>>>(roi, cls_loc, score, size, wg_w, prob, label, bbox, keys, wgwb);
    k_rank<<<16, 256, 0, stream>>>(keys, prob, label, bbox, order, sprob, sbbox, sgeo, out);
    k_geoemb<<<1280, 256, 0, stream>>>(order, app, feat_w, rank_w, part,
                                       sbbox, sgeo, wgwb, wg_b, lwbuf);
    k_embsum<<<512, 256, 0, stream>>>(part, feat_b, rank_b, embb);
    k_qkv2<<<dim3(8, 16, 3), 256, 0, stream>>>(embb, wq_w, wq_b, wk_w, wk_b, wv_w, wv_b, q, k, v);
    k_attn4<<<dim3(16, 16, NS), 256, 0, stream>>>(q, k, v, lwbuf, opartb, mpart, zpart);
    k_final2<<<1024, 128, 0, stream>>>(opartb, mpart, zpart, order, app, logit_w, logit_b, sprob, out);
}

// Round 8
// 167.868 us; speedup vs baseline: 1.1037x; 1.0028x over previous
//
#include <hip/hip_runtime.h>
#include <hip/hip_bf16.h>
#include <math.h>

typedef unsigned long long u64;
typedef unsigned int u32;
typedef __hip_bfloat16 bf16;

#define N 1024
#define NCLS 21
#define APP 1024
#define DF 128
#define NH 16
#define DK 64
#define NS 2     // n-splits in flash attention

typedef __attribute__((ext_vector_type(8))) short short8v;
typedef __attribute__((ext_vector_type(4))) float float4v;
union U4S8 { uint4 u; short8v s; };

__device__ __forceinline__ float b2f(bf16 x) { return __bfloat162float(x); }
__device__ __forceinline__ ushort f2bu(float x) { bf16 b = __float2bfloat16(x); return *(ushort*)&b; }
__device__ __forceinline__ float bu2f(ushort u) { return __uint_as_float(((uint)u) << 16); }

// ---------------------------------------------------------------- k_prep
__global__ void k_prep(const float* __restrict__ roi, const float* __restrict__ cls_loc,
                       const float* __restrict__ score, const int* __restrict__ size,
                       const float* __restrict__ wgw,
                       float* __restrict__ prob, int* __restrict__ label,
                       float* __restrict__ bbox, u64* __restrict__ keys,
                       ushort* __restrict__ wgwb)
{
    int i = blockIdx.x * 256 + threadIdx.x;
    if (i >= N) return;
    // one-time bf16 conversion of wgw [16][64] (exactly 1024 elements)
    wgwb[i] = f2bu(wgw[i]);

    float s[NCLS];
    float mx = -1e30f; int am = 0;
    for (int c = 0; c < NCLS; c++) {
        s[c] = score[i * NCLS + c];
        if (s[c] > mx) { mx = s[c]; am = c; }
    }
    float sum = 0.f;
    for (int c = 0; c < NCLS; c++) sum += expf(s[c] - mx);
    float p = 1.0f / sum;

    float y0 = roi[i*4+0], x0 = roi[i*4+1];
    float y1 = roi[i*4+2], x1 = roi[i*4+3];
    float hh = y1 - y0, ww = x1 - x0;
    float cy = y0 + 0.5f * hh, cx = x0 + 0.5f * ww;
    float l0 = cls_loc[i*84 + am*4 + 0] * 0.1f;
    float l1 = cls_loc[i*84 + am*4 + 1] * 0.1f;
    float l2 = cls_loc[i*84 + am*4 + 2] * 0.2f;
    float l3 = cls_loc[i*84 + am*4 + 3] * 0.2f;
    float ncy = l0 * hh + cy, ncx = l1 * ww + cx;
    float nh = expf(l2) * hh, nw = expf(l3) * ww;
    float b0 = ncy - 0.5f * nh, b1 = ncx - 0.5f * nw;
    float b2v = ncy + 0.5f * nh, b3 = ncx + 0.5f * nw;
    float lim = ((am & 1) == 0) ? (float)size[0] : (float)size[1];
    b0  = fminf(fmaxf(b0, 0.f), lim);
    b1  = fminf(fmaxf(b1, 0.f), lim);
    b2v = fminf(fmaxf(b2v, 0.f), lim);
    b3  = fminf(fmaxf(b3, 0.f), lim);
    prob[i] = p; label[i] = am;
    bbox[i*4+0] = b0; bbox[i*4+1] = b1; bbox[i*4+2] = b2v; bbox[i*4+3] = b3;
    keys[i] = ((u64)(0xFFFFFFFFu - __float_as_uint(p)) << 32) | (u32)i;
}

// ---------------------------------------------------------------- k_rank (4-way split count)
__global__ void __launch_bounds__(256) k_rank(
        const u64* __restrict__ keys, const float* __restrict__ prob,
        const int* __restrict__ label, const float* __restrict__ bbox,
        int* __restrict__ order, float* __restrict__ sprob,
        float* __restrict__ sbbox, float* __restrict__ sgeo,
        float* __restrict__ out)
{
    __shared__ u64 sk[N];
    int t = threadIdx.x;
    for (int j = t; j < N; j += 256) sk[j] = keys[j];
    __syncthreads();
    int il = t >> 2, q = t & 3;           // 64 elements/block, 4 counters each
    int i = blockIdx.x * 64 + il;
    u64 my = sk[i];
    int r = 0;
    int j0 = q * 256;
    #pragma unroll 8
    for (int j = j0; j < j0 + 256; j++) r += (sk[j] < my) ? 1 : 0;
    r += __shfl_xor(r, 1, 64);
    r += __shfl_xor(r, 2, 64);
    if (q == 0) {
        order[r] = i;
        sprob[r] = prob[i];
        float b0 = bbox[i*4+0], b1 = bbox[i*4+1], b2 = bbox[i*4+2], b3 = bbox[i*4+3];
        sbbox[r*4+0] = b0; sbbox[r*4+1] = b1; sbbox[r*4+2] = b2; sbbox[r*4+3] = b3;
        // per-box geo precompute: (cx, cy, log w, log h) in sorted order
        sgeo[r*4+0] = (b0 + b2) * 0.5f;
        sgeo[r*4+1] = (b1 + b3) * 0.5f;
        sgeo[r*4+2] = __logf(b2 - b0 + 1.0f);
        sgeo[r*4+3] = __logf(b3 - b1 + 1.0f);
        out[N + r] = (float)(label[i] - 1);
        out[2*N + r*4 + 0] = b0;
        out[2*N + r*4 + 1] = b1;
        out[2*N + r*4 + 2] = b2;
        out[2*N + r*4 + 3] = b3;
    }
}

// ---------------------------------------------------------------- k_geoemb (horizontal fusion)
// blocks 0..255: emb body FIRST (16 rt x 8 dg x 2 ph) -> part  (overlaps geo)
// blocks 256..1279: geo body, ONE block per m, 16-iter inner loop -> lw
__global__ void __launch_bounds__(256) k_geoemb(
        const int* __restrict__ order, const float* __restrict__ app,
        const float* __restrict__ feat_w, const float* __restrict__ rank_w,
        float* __restrict__ part,
        const float* __restrict__ sbbox, const float* __restrict__ sgeo,
        const ushort* __restrict__ wgwb,
        const float* __restrict__ wgb, bf16* __restrict__ lw)
{
    __shared__ __align__(16) char smem[33024];
    int bx = blockIdx.x, t = threadIdx.x;
    int w = t >> 6, l = t & 63, l15 = l & 15, quad = l >> 4;

    if (bx >= 256) {
        // ===================== geo body =====================
        uint (*sOut)[516] = (uint(*)[516])smem;   // 16 x 516 x 4 = 33024 B
        int m = bx - 256;

        // block-uniform m-side scalars
        float4 mg = *(const float4*)&sgeo[m*4];   // cx, cy, logw, logh
        float4 mb = *(const float4*)&sbbox[m*4];
        float wm = mb.z - mb.x + 1.0f, hm = mb.w - mb.y + 1.0f;

        // per-lane quad-dependent constants (hoisted out of the loop)
        float sC  = (quad == 0) ? mg.x : (quad == 1) ? mg.y : 0.0f;
        float sM  = ((quad & 1) == 0) ? 1e-3f * wm : 1e-3f * hm;
        float sL  = ((quad & 1) == 0) ? mg.z : mg.w;   // log wm / log hm
        float sSg = (quad < 2) ? 100.0f : -100.0f;

        // pre-converted bf16 geo weights: 2 vector loads
        U4S8 Bg0, Bg1;
        const uint4* wg4 = (const uint4*)wgwb;
        Bg0.u = wg4[l15*8 + quad];
        Bg1.u = wg4[l15*8 + 4 + quad];
        float bias = wgb[l15];

        const float dmt[8] = { 1.0f, 0.42169650342f, 0.177827941f, 0.0749894209f,
                               0.0316227766f, 0.01333521432f, 0.00562341325f, 0.00237137371f };

        #pragma unroll 4
        for (int mt2 = 0; mt2 < 16; mt2++) {
            int n = mt2*64 + w*16 + l15;
            float valn = sgeo[n*4 + quad];            // 4B load, pipelined by unroll
            float lg = __logf(fmaxf(fabsf(sC - valn), sM));
            float lv = (quad < 2) ? lg : valn;        // q2/3: precomputed log wn / log hn
            float P  = sSg * (lv - sL);               // = 100*pos component

            U4S8 Af0, Af1;   // sin half (g=0..31), cos half (g=32..63)
            #pragma unroll
            for (int j = 0; j < 4; j++) {
                float s0, c0, s1, c1;
                __sincosf(P * dmt[2*j],     &s0, &c0);
                __sincosf(P * dmt[2*j + 1], &s1, &c1);
                ((uint*)&Af0)[j] = (uint)f2bu(s0) | ((uint)f2bu(s1) << 16);
                ((uint*)&Af1)[j] = (uint)f2bu(c0) | ((uint)f2bu(c1) << 16);
            }

            float4v c = (float4v){0.f, 0.f, 0.f, 0.f};
            c = __builtin_amdgcn_mfma_f32_16x16x32_bf16(Af0.s, Bg0.s, c, 0, 0, 0);
            c = __builtin_amdgcn_mfma_f32_16x16x32_bf16(Af1.s, Bg1.s, c, 0, 0, 0);
            float v0 = __logf(fmaxf(c[0] + bias, 1e-6f));
            float v1 = __logf(fmaxf(c[1] + bias, 1e-6f));
            float v2 = __logf(fmaxf(c[2] + bias, 1e-6f));
            float v3 = __logf(fmaxf(c[3] + bias, 1e-6f));
            int pb = mt2*32 + w*8 + quad*2;
            sOut[l15][pb]     = (uint)f2bu(v0) | ((uint)f2bu(v1) << 16);
            sOut[l15][pb + 1] = (uint)f2bu(v2) | ((uint)f2bu(v3) << 16);
        }
        __syncthreads();
        uint* lwu = (uint*)lw;
        #pragma unroll
        for (int it = 0; it < 8; it++) {
            int idx = t + it * 256;            // 2048 uint4 = 16 h x 128
            int hh = idx >> 7, col4 = idx & 127;
            uint4 val = *(const uint4*)&sOut[hh][col4*4];
            *(uint4*)&lwu[((size_t)hh << 19) + ((size_t)m << 9) + col4*4] = val;
        }
    } else {
        // ===================== emb body =====================
        ushort (*sA)[72] = (ushort(*)[72])smem;             // 9216 B
        ushort (*sW)[72] = (ushort(*)[72])(smem + 9216);    // 18432 B
        int* sOrd = (int*)(smem + 27648);                   // 256 B
        int idx0 = bx;
        int rt = idx0 & 15, dg = (idx0 >> 4) & 7, ph = idx0 >> 7;
        int r0 = rt * 64;
        if (t < 64) sOrd[t] = order[r0 + t];
        __syncthreads();

        const float* Wsrc = ph ? rank_w : feat_w;
        float4v acc[8];
        #pragma unroll
        for (int nb = 0; nb < 8; nb++) acc[nb] = (float4v){0.f, 0.f, 0.f, 0.f};

        for (int dc = dg * 2; dc < dg * 2 + 2; dc++) {
            int d0 = dc * 64;
            #pragma unroll
            for (int it = 0; it < 32; it++) {
                int idx = t + it * 256;
                int d = idx >> 7, c = idx & 127;
                sW[c][d] = f2bu(Wsrc[(size_t)(d0 + d) * 128 + c]);
            }
            if (ph == 0) {
                #pragma unroll
                for (int it = 0; it < 16; it++) {
                    int idx = t + it * 256;
                    int r = idx >> 6, d = idx & 63;
                    sA[r][d] = f2bu(app[(size_t)sOrd[r] * 1024 + d0 + d]);
                }
            } else {
                #pragma unroll
                for (int it = 0; it < 16; it++) {
                    int idx = t + it * 256;
                    int r = idx >> 6, d = idx & 63;
                    int dgl = d0 + d;
                    float irow = (float)(r0 + r);
                    float val;
                    if (dgl < 512) val = __sinf(irow * exp2f(-(float)dgl * 0.019464422f));
                    else           val = __cosf(irow * exp2f(-(float)(dgl - 512) * 0.019464422f));
                    sA[r][d] = f2bu(val);
                }
            }
            __syncthreads();
            U4S8 Af0, Af1;
            Af0.u = *(uint4*)&sA[w*16 + l15][quad*8];
            Af1.u = *(uint4*)&sA[w*16 + l15][32 + quad*8];
            #pragma unroll
            for (int nb = 0; nb < 8; nb++) {
                U4S8 Bf0, Bf1;
                Bf0.u = *(uint4*)&sW[nb*16 + l15][quad*8];
                Bf1.u = *(uint4*)&sW[nb*16 + l15][32 + quad*8];
                acc[nb] = __builtin_amdgcn_mfma_f32_16x16x32_bf16(Af0.s, Bf0.s, acc[nb], 0, 0, 0);
                acc[nb] = __builtin_amdgcn_mfma_f32_16x16x32_bf16(Af1.s, Bf1.s, acc[nb], 0, 0, 0);
            }
            __syncthreads();
        }
        #pragma unroll
        for (int reg = 0; reg < 4; reg++) {
            int row = r0 + w*16 + quad*4 + reg;
            #pragma unroll
            for (int nb = 0; nb < 8; nb++)
                part[(((size_t)ph * 8 + dg) * 1024 + row) * 128 + nb*16 + l15] = acc[nb][reg];
        }
    }
}

// ---------------------------------------------------------------- k_embsum (-> bf16)
__global__ void k_embsum(const float* __restrict__ part,
                         const float* __restrict__ feat_b, const float* __restrict__ rank_b,
                         bf16* __restrict__ embb)
{
    int gid = blockIdx.x * 256 + threadIdx.x;
    int c = gid & 127;
    float acc = feat_b[c] + rank_b[c];
    #pragma unroll
    for (int p8 = 0; p8 < 16; p8++) acc += part[(size_t)p8 * 131072 + gid];
    embb[gid] = __float2bfloat16(acc);
}

// ---------------------------------------------------------------- k_qkv2 (MFMA)
__global__ void __launch_bounds__(256) k_qkv2(
        const bf16* __restrict__ embb,
        const float* __restrict__ wq, const float* __restrict__ bq,
        const float* __restrict__ wk, const float* __restrict__ bk,
        const float* __restrict__ wv, const float* __restrict__ bv,
        bf16* __restrict__ q, bf16* __restrict__ k, bf16* __restrict__ v)
{
    __shared__ ushort sWt[64][136];
    int t = threadIdx.x;
    int rt = blockIdx.x, h = blockIdx.y, mat = blockIdx.z;
    const float* W  = (mat == 0) ? wq : (mat == 1) ? wk : wv;
    const float* Bb = (mat == 0) ? bq : (mat == 1) ? bk : bv;
    bf16* Out       = (mat == 0) ? q  : (mat == 1) ? k  : v;

    #pragma unroll
    for (int i = 0; i < 32; i++) {
        int idx = t + i * 256;
        int d = idx >> 6, kk = idx & 63;
        sWt[kk][d] = f2bu(W[((size_t)h * 128 + d) * 64 + kk]);
    }
    int w = t >> 6, l = t & 63, l15 = l & 15, quad = l >> 4;
    float biasv[4];
    #pragma unroll
    for (int nb = 0; nb < 4; nb++) biasv[nb] = Bb[h * 64 + nb*16 + l15];
    __syncthreads();

    U4S8 Bf[4][4];
    #pragma unroll
    for (int nb = 0; nb < 4; nb++)
        #pragma unroll
        for (int kc = 0; kc < 4; kc++)
            Bf[nb][kc].u = *(uint4*)&sWt[nb*16 + l15][kc*32 + quad*8];

    const uint4* A4 = (const uint4*)embb;
    int r0 = rt * 128 + w * 32;
    ushort* outu = (ushort*)Out;
    for (int mb = 0; mb < 2; mb++) {
        int arow = r0 + mb*16 + l15;
        U4S8 Af[4];
        #pragma unroll
        for (int kc = 0; kc < 4; kc++) Af[kc].u = A4[(size_t)arow * 16 + kc*4 + quad];
        float4v acc[4];
        #pragma unroll
        for (int nb = 0; nb < 4; nb++) acc[nb] = (float4v){0.f, 0.f, 0.f, 0.f};
        #pragma unroll
        for (int kc = 0; kc < 4; kc++)
            #pragma unroll
            for (int nb = 0; nb < 4; nb++)
                acc[nb] = __builtin_amdgcn_mfma_f32_16x16x32_bf16(Af[kc].s, Bf[nb][kc].s, acc[nb], 0, 0, 0);
        #pragma unroll
        for (int reg = 0; reg < 4; reg++) {
            int orow = r0 + mb*16 + quad*4 + reg;
            #pragma unroll
            for (int nb = 0; nb < 4; nb++)
                outu[((size_t)h * N + orow) * 64 + nb*16 + l15] = f2bu(acc[nb][reg] + biasv[nb]);
        }
    }
}

// ---------------------------------------------------------------- k_attn4 (MFMA flash, n-split)
// T14 async-STAGE split: next tile's 24 global loads are issued into registers
// BEFORE the current tile's compute (latency hides under MFMA+softmax), and the
// regs->LDS writes land after the compute-side barrier.
__global__ void __launch_bounds__(256) k_attn4(
        const bf16* __restrict__ q, const bf16* __restrict__ kmat,
        const bf16* __restrict__ v, const bf16* __restrict__ lw,
        bf16* __restrict__ opartb, float* __restrict__ mpart, float* __restrict__ zpart)
{
    __shared__ uint sQu[64][36];
    __shared__ uint sVtu[64][36];
    __shared__ uint slwu[64][36];
    __shared__ uint sPu[4][16][36];

    int t = threadIdx.x;
    int mt = blockIdx.x, h = blockIdx.y, ns = blockIdx.z;
    int m0 = mt * 64;
    int w = t >> 6, l = t & 63, l15 = l & 15, quad = l >> 4;

    U4S8 kf0, kf1;
    {
        const uint4* k4 = (const uint4*)kmat;
        size_t krow = ((size_t)h * N + m0 + w*16 + l15) * 8;
        kf0.u = k4[krow + quad];
        kf1.u = k4[krow + 4 + quad];
    }

    float4v O[4];
    float M[4], Z[4];
    #pragma unroll
    for (int i = 0; i < 4; i++) {
        O[i] = (float4v){0.f, 0.f, 0.f, 0.f};
        M[i] = -1e30f; Z[i] = 0.f;
    }

    const uint* qsrc = (const uint*)q;
    const uint* vsrc = (const uint*)v;
    const uint* lwsrc = (const uint*)lw;

    uint rq[8], rv0[4], rv1[4], rlw[8];
    int tile0 = ns * (16/NS), tileE = tile0 + (16/NS);

    // prologue: load + write tile0
    {
        int n0 = tile0 * 64;
        #pragma unroll
        for (int i = 0; i < 8; i++) {
            int idx = t + i * 256; int nj = idx >> 5, kp = idx & 31;
            rq[i] = qsrc[((size_t)h * N + n0 + nj) * 32 + kp];
        }
        #pragma unroll
        for (int i = 0; i < 4; i++) {
            int idx = t + i * 256; int a = idx & 31, nh2 = idx >> 5;
            rv0[i] = vsrc[((size_t)h * N + n0 + 2*nh2) * 32 + a];
            rv1[i] = vsrc[((size_t)h * N + n0 + 2*nh2 + 1) * 32 + a];
        }
        #pragma unroll
        for (int i = 0; i < 8; i++) {
            int idx = t + i * 256; int mi = idx >> 5, np = idx & 31;
            rlw[i] = lwsrc[((size_t)h << 19) + ((size_t)(m0 + mi) << 9) + (n0 >> 1) + np];
        }
        #pragma unroll
        for (int i = 0; i < 8; i++) { int idx = t + i * 256; sQu[idx >> 5][idx & 31] = rq[i]; }
        #pragma unroll
        for (int i = 0; i < 4; i++) {
            int idx = t + i * 256; int a = idx & 31, nh2 = idx >> 5;
            sVtu[2*a][nh2]     = (rv0[i] & 0xFFFFu) | (rv1[i] << 16);
            sVtu[2*a + 1][nh2] = (rv0[i] >> 16) | (rv1[i] & 0xFFFF0000u);
        }
        #pragma unroll
        for (int i = 0; i < 8; i++) { int idx = t + i * 256; slwu[idx >> 5][idx & 31] = rlw[i]; }
    }
    __syncthreads();

    for (int tile = tile0; tile < tileE; tile++) {
        bool more = (tile + 1 < tileE);
        if (more) {
            // issue next tile's loads EARLY (registers); consumed after next barrier
            int n0 = (tile + 1) * 64;
            #pragma unroll
            for (int i = 0; i < 8; i++) {
                int idx = t + i * 256; int nj = idx >> 5, kp = idx & 31;
                rq[i] = qsrc[((size_t)h * N + n0 + nj) * 32 + kp];
            }
            #pragma unroll
            for (int i = 0; i < 4; i++) {
                int idx = t + i * 256; int a = idx & 31, nh2 = idx >> 5;
                rv0[i] = vsrc[((size_t)h * N + n0 + 2*nh2) * 32 + a];
                rv1[i] = vsrc[((size_t)h * N + n0 + 2*nh2 + 1) * 32 + a];
            }
            #pragma unroll
            for (int i = 0; i < 8; i++) {
                int idx = t + i * 256; int mi = idx >> 5, np = idx & 31;
                rlw[i] = lwsrc[((size_t)h << 19) + ((size_t)(m0 + mi) << 9) + (n0 >> 1) + np];
            }
        }

        // ---- compute current tile from LDS ----
        float4v S[4];
        #pragma unroll
        for (int nb = 0; nb < 4; nb++) {
            U4S8 bq0, bq1;
            bq0.u = *(uint4*)&sQu[nb*16 + l15][quad*4];
            bq1.u = *(uint4*)&sQu[nb*16 + l15][16 + quad*4];
            float4v zz = (float4v){0.f, 0.f, 0.f, 0.f};
            float4v p0 = __builtin_amdgcn_mfma_f32_16x16x32_bf16(kf0.s, bq0.s, zz, 0, 0, 0);
            S[nb] = __builtin_amdgcn_mfma_f32_16x16x32_bf16(kf1.s, bq1.s, p0, 0, 0, 0);
        }
        ushort* pRow[4];
        #pragma unroll
        for (int r = 0; r < 4; r++) pRow[r] = (ushort*)&sPu[w][quad*4 + r][0];
        #pragma unroll
        for (int r = 0; r < 4; r++) {
            int mi = w*16 + quad*4 + r;
            float sv[4];
            #pragma unroll
            for (int nb = 0; nb < 4; nb++) {
                int col = nb*16 + l15;
                uint lu = slwu[mi][col >> 1];
                float lv = (col & 1) ? __uint_as_float(lu & 0xFFFF0000u)
                                     : __uint_as_float(lu << 16);
                sv[nb] = S[nb][r] * 0.125f + lv;
            }
            float rm = fmaxf(fmaxf(sv[0], sv[1]), fmaxf(sv[2], sv[3]));
            #pragma unroll
            for (int off = 1; off < 16; off <<= 1)
                rm = fmaxf(rm, __shfl_xor(rm, off, 64));
            float newM = fmaxf(M[r], rm);
            float pr[4], rs = 0.f;
            #pragma unroll
            for (int nb = 0; nb < 4; nb++) {
                pr[nb] = __expf(sv[nb] - newM);
                rs += pr[nb];
            }
            #pragma unroll
            for (int off = 1; off < 16; off <<= 1)
                rs += __shfl_xor(rs, off, 64);
            float sc = __expf(M[r] - newM);
            M[r] = newM;
            Z[r] = Z[r] * sc + rs;
            #pragma unroll
            for (int kvb = 0; kvb < 4; kvb++) O[kvb][r] *= sc;
            #pragma unroll
            for (int nb = 0; nb < 4; nb++)
                pRow[r][nb*16 + l15] = f2bu(pr[nb]);
        }
        {
            U4S8 ap0, ap1;
            ap0.u = *(uint4*)&sPu[w][l15][quad*4];
            ap1.u = *(uint4*)&sPu[w][l15][16 + quad*4];
            #pragma unroll
            for (int kvb = 0; kvb < 4; kvb++) {
                U4S8 bv0, bv1;
                bv0.u = *(uint4*)&sVtu[kvb*16 + l15][quad*4];
                bv1.u = *(uint4*)&sVtu[kvb*16 + l15][16 + quad*4];
                O[kvb] = __builtin_amdgcn_mfma_f32_16x16x32_bf16(ap0.s, bv0.s, O[kvb], 0, 0, 0);
                O[kvb] = __builtin_amdgcn_mfma_f32_16x16x32_bf16(ap1.s, bv1.s, O[kvb], 0, 0, 0);
            }
        }
        __syncthreads();          // all waves done reading this tile's LDS

        if (more) {
            // write-late: loads issued a full compute-phase ago are complete
            #pragma unroll
            for (int i = 0; i < 8; i++) { int idx = t + i * 256; sQu[idx >> 5][idx & 31] = rq[i]; }
            #pragma unroll
            for (int i = 0; i < 4; i++) {
                int idx = t + i * 256; int a = idx & 31, nh2 = idx >> 5;
                sVtu[2*a][nh2]     = (rv0[i] & 0xFFFFu) | (rv1[i] << 16);
                sVtu[2*a + 1][nh2] = (rv0[i] >> 16) | (rv1[i] & 0xFFFF0000u);
            }
            #pragma unroll
            for (int i = 0; i < 8; i++) { int idx = t + i * 256; slwu[idx >> 5][idx & 31] = rlw[i]; }
            __syncthreads();
        }
    }

    ushort* ob = (ushort*)opartb;
    #pragma unroll
    for (int r = 0; r < 4; r++) {
        int m = m0 + w*16 + quad*4 + r;
        size_t row = ((size_t)ns * NH + h) * N + m;
        #pragma unroll
        for (int kvb = 0; kvb < 4; kvb++)
            ob[row * 64 + kvb*16 + l15] = f2bu(O[kvb][r]);
        if (l15 == 0) { mpart[row] = M[r]; zpart[row] = Z[r]; }
    }
}

// ---------------------------------------------------------------- k_final2 (merge + logit)
__global__ void __launch_bounds__(128) k_final2(
        const bf16* __restrict__ opartb, const float* __restrict__ mpart,
        const float* __restrict__ zpart, const int* __restrict__ order,
        const float* __restrict__ app, const float* __restrict__ lw,
        const float* __restrict__ lb, const float* __restrict__ sprob,
        float* __restrict__ out)
{
    __shared__ float sWgt[NH][NS];
    __shared__ float sInvZ[NH];
    __shared__ float red[2];
    int m = blockIdx.x, t = threadIdx.x;
    if (t < NH) {
        int h = t;
        float Ms[NS], Mg = -1e30f;
        #pragma unroll
        for (int ns = 0; ns < NS; ns++) {
            Ms[ns] = mpart[(size_t)ns * 16384 + h * 1024 + m];
            Mg = fmaxf(Mg, Ms[ns]);
        }
        float Zt = 0.f;
        #pragma unroll
        for (int ns = 0; ns < NS; ns++) {
            float wgt = __expf(Ms[ns] - Mg);
            sWgt[h][ns] = wgt;
            Zt += zpart[(size_t)ns * 16384 + h * 1024 + m] * wgt;
        }
        sInvZ[h] = 1.0f / Zt;
    }
    __syncthreads();
    int o = order[m];
    const ushort* ob = (const ushort*)opartb;
    float s = 0.f;
    for (int j = t; j < APP; j += 128) {
        int hh = j >> 6, kk = j & 63;
        size_t base = ((size_t)hh * 1024 + m) * 64 + kk;
        float val = 0.f;
        #pragma unroll
        for (int ns = 0; ns < NS; ns++)
            val += bu2f(ob[(size_t)ns * 1048576 + base]) * sWgt[hh][ns];
        float rv = val * sInvZ[hh] + app[o * APP + j];
        s += rv * lw[j];
    }
    #pragma unroll
    for (int off = 32; off > 0; off >>= 1) s += __shfl_down(s, off, 64);
    if ((t & 63) == 0) red[t >> 6] = s;
    __syncthreads();
    if (t == 0) {
        float tot = red[0] + red[1] + lb[0];
        float s1 = 1.0f / (1.0f + expf(-tot));
        out[m] = s1 * sprob[m];
    }
}

// ---------------------------------------------------------------- launch
extern "C" void kernel_launch(void* const* d_in, const int* in_sizes, int n_in,
                              void* d_out, int out_size, void* d_ws, size_t ws_size,
                              hipStream_t stream)
{
    const float* roi      = (const float*)d_in[0];
    const float* cls_loc  = (const float*)d_in[1];
    const float* score    = (const float*)d_in[2];
    const float* app      = (const float*)d_in[3];
    const int*   size     = (const int*)d_in[4];
    const float* rank_w   = (const float*)d_in[5];
    const float* rank_b   = (const float*)d_in[6];
    const float* feat_w   = (const float*)d_in[7];
    const float* feat_b   = (const float*)d_in[8];
    const float* logit_w  = (const float*)d_in[9];
    const float* logit_b  = (const float*)d_in[10];
    const float* wg_w     = (const float*)d_in[11];
    const float* wg_b     = (const float*)d_in[12];
    const float* wk_w     = (const float*)d_in[13];
    const float* wk_b     = (const float*)d_in[14];
    const float* wq_w     = (const float*)d_in[15];
    const float* wq_b     = (const float*)d_in[16];
    const float* wv_w     = (const float*)d_in[17];
    const float* wv_b     = (const float*)d_in[18];
    float* out = (float*)d_out;

    char* ws = (char*)d_ws;
    float* prob  = (float*)(ws + 0);
    int*   label = (int*)  (ws + 4096);
    float* bbox  = (float*)(ws + 8192);
    u64*   keys  = (u64*)  (ws + 24576);
    int*   order = (int*)  (ws + 32768);
    float* sprob = (float*)(ws + 36864);
    float* sbbox = (float*)(ws + 40960);
    bf16*  embb  = (bf16*) (ws + 57344);      // 256 KB
    ushort* wgwb = (ushort*)(ws + 1048576);   // 2 KB   bf16 wgw [16][64]
    float* sgeo  = (float*)(ws + 1052672);    // 16 KB  (cx,cy,logw,logh) sorted
    bf16*  q     = (bf16*) (ws + 8970240);    // 2 MB
    bf16*  k     = (bf16*) (ws + 11067392);   // 2 MB
    bf16*  v     = (bf16*) (ws + 13164544);   // 2 MB
    bf16*  lwbuf = (bf16*) (ws + 17358848);   // 32 MB
    float* part  = (float*)(ws + 50913280);   // 8 MB   [16][1024][128] f32
    bf16*  opartb= (bf16*) (ws + 67690496);   // 4 MB   [NS][16384][64] bf16
    float* mpart = (float*)(ws + 84467712);   // 128 KB [NS][16384]
    float* zpart = (float*)(ws + 84729856);   // 128 KB

    k_prep<<<4, 256, 0, stream>>>(roi, cls_loc, score, size, wg_w, prob, label, bbox, keys, wgwb);
    k_rank<<<16, 256, 0, stream>>>(keys, prob, label, bbox, order, sprob, sbbox, sgeo, out);
    k_geoemb<<<1280, 256, 0, stream>>>(order, app, feat_w, rank_w, part,
                                       sbbox, sgeo, wgwb, wg_b, lwbuf);
    k_embsum<<<512, 256, 0, stream>>>(part, feat_b, rank_b, embb);
    k_qkv2<<<dim3(8, 16, 3), 256, 0, stream>>>(embb, wq_w, wq_b, wk_w, wk_b, wv_w, wv_b, q, k, v);
    k_attn4<<<dim3(16, 16, NS), 256, 0, stream>>>(q, k, v, lwbuf, opartb, mpart, zpart);
    k_final2<<<1024, 128, 0, stream>>>(opartb, mpart, zpart, order, app, logit_w, logit_b, sprob, out);
}